// Round 11
// baseline (181.808 us; speedup 1.0000x reference)
//
#include <hip/hip_runtime.h>

constexpr int IN_F   = 32;
constexpr int OUT_F  = 128;
constexpr int BLOCK  = 256;
constexpr int WAVES  = BLOCK / 64;
constexpr int RSTAGE = 8;

using f32x2  = __attribute__((ext_vector_type(2)))  float;
using f32x16 = __attribute__((ext_vector_type(16))) float;

// ---------------- V0: R7 control (scalar FMA, syncthreads) ----------------
__global__ __launch_bounds__(BLOCK, 4)
void rbf_v0(const float* __restrict__ x, const float* __restrict__ centres,
            const float* __restrict__ log_sigmas, float* __restrict__ out,
            int rows_per_wave)
{
    __shared__ float4 xs[WAVES][RSTAGE][IN_F / 4];
    __shared__ float  x2s[WAVES][RSTAGE];
    const int tid = threadIdx.x, wv = tid >> 6, lane = tid & 63;
    const int o0 = lane * 2;
    const f32x16 c0lo = *reinterpret_cast<const f32x16*>(centres + (size_t)(o0+0)*IN_F);
    const f32x16 c0hi = *reinterpret_cast<const f32x16*>(centres + (size_t)(o0+0)*IN_F + 16);
    const f32x16 c1lo = *reinterpret_cast<const f32x16*>(centres + (size_t)(o0+1)*IN_F);
    const f32x16 c1hi = *reinterpret_cast<const f32x16*>(centres + (size_t)(o0+1)*IN_F + 16);
    float c2a = 0.f, c2b = 0.f;
    #pragma unroll
    for (int k = 0; k < 16; ++k) {
        c2a = fmaf(c0lo[k], c0lo[k], c2a); c2a = fmaf(c0hi[k], c0hi[k], c2a);
        c2b = fmaf(c1lo[k], c1lo[k], c2b); c2b = fmaf(c1hi[k], c1hi[k], c2b);
    }
    const float iv0 = __expf(-2.0f * log_sigmas[o0+0]);
    const float iv1 = __expf(-2.0f * log_sigmas[o0+1]);
    const size_t waveRow0 = ((size_t)blockIdx.x * WAVES + wv) * (size_t)rows_per_wave;
    const int rs = lane >> 3, q = lane & 7;

    for (int it = 0; it < rows_per_wave; it += RSTAGE) {
        const float4 v = *reinterpret_cast<const float4*>(x + (waveRow0+it)*IN_F + lane*4);
        float ss = v.x*v.x; ss = fmaf(v.y,v.y,ss); ss = fmaf(v.z,v.z,ss); ss = fmaf(v.w,v.w,ss);
        ss += __shfl_xor(ss,1); ss += __shfl_xor(ss,2); ss += __shfl_xor(ss,4);
        xs[wv][rs][q] = v;
        if (q == 0) x2s[wv][rs] = ss;
        __syncthreads();
        #pragma unroll
        for (int rr = 0; rr < RSTAGE; ++rr) {
            float acc0 = 0.f, acc1 = 0.f;
            #pragma unroll
            for (int u = 0; u < 4; ++u) {
                const float4 xq = xs[wv][rr][u];
                acc0 = fmaf(xq.x,c0lo[4*u+0],acc0); acc0 = fmaf(xq.y,c0lo[4*u+1],acc0);
                acc0 = fmaf(xq.z,c0lo[4*u+2],acc0); acc0 = fmaf(xq.w,c0lo[4*u+3],acc0);
                acc1 = fmaf(xq.x,c1lo[4*u+0],acc1); acc1 = fmaf(xq.y,c1lo[4*u+1],acc1);
                acc1 = fmaf(xq.z,c1lo[4*u+2],acc1); acc1 = fmaf(xq.w,c1lo[4*u+3],acc1);
            }
            #pragma unroll
            for (int u = 0; u < 4; ++u) {
                const float4 xq = xs[wv][rr][4+u];
                acc0 = fmaf(xq.x,c0hi[4*u+0],acc0); acc0 = fmaf(xq.y,c0hi[4*u+1],acc0);
                acc0 = fmaf(xq.z,c0hi[4*u+2],acc0); acc0 = fmaf(xq.w,c0hi[4*u+3],acc0);
                acc1 = fmaf(xq.x,c1hi[4*u+0],acc1); acc1 = fmaf(xq.y,c1hi[4*u+1],acc1);
                acc1 = fmaf(xq.z,c1hi[4*u+2],acc1); acc1 = fmaf(xq.w,c1hi[4*u+3],acc1);
            }
            const float x2 = x2s[wv][rr];
            const float t0 = fmaxf(fmaf(-2.0f,acc0,x2+c2a),0.0f);
            const float t1 = fmaxf(fmaf(-2.0f,acc1,x2+c2b),0.0f);
            f32x2 o; o.x = __expf(-t0*iv0); o.y = __expf(-t1*iv1);
            __builtin_nontemporal_store(o,
                reinterpret_cast<f32x2*>(out + (waveRow0+it+rr)*OUT_F + o0));
        }
        __syncthreads();
    }
}

// ------------- V1: packed v_pk_fma_f32 over k-pairs (syncthreads) ----------
__global__ __launch_bounds__(BLOCK, 4)
void rbf_v1(const float* __restrict__ x, const float* __restrict__ centres,
            const float* __restrict__ log_sigmas, float* __restrict__ out,
            int rows_per_wave)
{
    __shared__ float4 xs[WAVES][RSTAGE][IN_F / 4];
    __shared__ float  x2s[WAVES][RSTAGE];
    const int tid = threadIdx.x, wv = tid >> 6, lane = tid & 63;
    const int o0 = lane * 2;
    const f32x16 c0lo = *reinterpret_cast<const f32x16*>(centres + (size_t)(o0+0)*IN_F);
    const f32x16 c0hi = *reinterpret_cast<const f32x16*>(centres + (size_t)(o0+0)*IN_F + 16);
    const f32x16 c1lo = *reinterpret_cast<const f32x16*>(centres + (size_t)(o0+1)*IN_F);
    const f32x16 c1hi = *reinterpret_cast<const f32x16*>(centres + (size_t)(o0+1)*IN_F + 16);
    float c2a = 0.f, c2b = 0.f;
    #pragma unroll
    for (int k = 0; k < 16; ++k) {
        c2a = fmaf(c0lo[k], c0lo[k], c2a); c2a = fmaf(c0hi[k], c0hi[k], c2a);
        c2b = fmaf(c1lo[k], c1lo[k], c2b); c2b = fmaf(c1hi[k], c1hi[k], c2b);
    }
    const float iv0 = __expf(-2.0f * log_sigmas[o0+0]);
    const float iv1 = __expf(-2.0f * log_sigmas[o0+1]);
    const size_t waveRow0 = ((size_t)blockIdx.x * WAVES + wv) * (size_t)rows_per_wave;
    const int rs = lane >> 3, q = lane & 7;

    for (int it = 0; it < rows_per_wave; it += RSTAGE) {
        const float4 v = *reinterpret_cast<const float4*>(x + (waveRow0+it)*IN_F + lane*4);
        float ss = v.x*v.x; ss = fmaf(v.y,v.y,ss); ss = fmaf(v.z,v.z,ss); ss = fmaf(v.w,v.w,ss);
        ss += __shfl_xor(ss,1); ss += __shfl_xor(ss,2); ss += __shfl_xor(ss,4);
        xs[wv][rs][q] = v;
        if (q == 0) x2s[wv][rs] = ss;
        __syncthreads();
        #pragma unroll
        for (int rr = 0; rr < RSTAGE; ++rr) {
            f32x2 a0 = {0.f,0.f}, a1 = {0.f,0.f};
            #pragma unroll
            for (int u = 0; u < 4; ++u) {
                const float4 xq = xs[wv][rr][u];
                const f32x2 e0 = {xq.x, xq.y}, e1 = {xq.z, xq.w};
                const f32x2 p00 = {c0lo[4*u+0], c0lo[4*u+1]}, p01 = {c0lo[4*u+2], c0lo[4*u+3]};
                const f32x2 p10 = {c1lo[4*u+0], c1lo[4*u+1]}, p11 = {c1lo[4*u+2], c1lo[4*u+3]};
                a0 = __builtin_elementwise_fma(e0, p00, a0);
                a0 = __builtin_elementwise_fma(e1, p01, a0);
                a1 = __builtin_elementwise_fma(e0, p10, a1);
                a1 = __builtin_elementwise_fma(e1, p11, a1);
            }
            #pragma unroll
            for (int u = 0; u < 4; ++u) {
                const float4 xq = xs[wv][rr][4+u];
                const f32x2 e0 = {xq.x, xq.y}, e1 = {xq.z, xq.w};
                const f32x2 p00 = {c0hi[4*u+0], c0hi[4*u+1]}, p01 = {c0hi[4*u+2], c0hi[4*u+3]};
                const f32x2 p10 = {c1hi[4*u+0], c1hi[4*u+1]}, p11 = {c1hi[4*u+2], c1hi[4*u+3]};
                a0 = __builtin_elementwise_fma(e0, p00, a0);
                a0 = __builtin_elementwise_fma(e1, p01, a0);
                a1 = __builtin_elementwise_fma(e0, p10, a1);
                a1 = __builtin_elementwise_fma(e1, p11, a1);
            }
            const float d0 = a0.x + a0.y, d1 = a1.x + a1.y;
            const float x2 = x2s[wv][rr];
            const float t0 = fmaxf(fmaf(-2.0f,d0,x2+c2a),0.0f);
            const float t1 = fmaxf(fmaf(-2.0f,d1,x2+c2b),0.0f);
            f32x2 o; o.x = __expf(-t0*iv0); o.y = __expf(-t1*iv1);
            __builtin_nontemporal_store(o,
                reinterpret_cast<f32x2*>(out + (waveRow0+it+rr)*OUT_F + o0));
        }
        __syncthreads();
    }
}

// ------- V2: packed + barrier-free wave-private double buffer (R3 sync) ----
__global__ __launch_bounds__(BLOCK, 4)
void rbf_v2(const float* __restrict__ x, const float* __restrict__ centres,
            const float* __restrict__ log_sigmas, float* __restrict__ out,
            int rows_per_wave)
{
    __shared__ float4 xs[WAVES][2][RSTAGE][IN_F / 4];
    __shared__ float  x2s[WAVES][2][RSTAGE];
    const int tid = threadIdx.x, wv = tid >> 6, lane = tid & 63;
    const int o0 = lane * 2;
    const f32x16 c0lo = *reinterpret_cast<const f32x16*>(centres + (size_t)(o0+0)*IN_F);
    const f32x16 c0hi = *reinterpret_cast<const f32x16*>(centres + (size_t)(o0+0)*IN_F + 16);
    const f32x16 c1lo = *reinterpret_cast<const f32x16*>(centres + (size_t)(o0+1)*IN_F);
    const f32x16 c1hi = *reinterpret_cast<const f32x16*>(centres + (size_t)(o0+1)*IN_F + 16);
    float c2a = 0.f, c2b = 0.f;
    #pragma unroll
    for (int k = 0; k < 16; ++k) {
        c2a = fmaf(c0lo[k], c0lo[k], c2a); c2a = fmaf(c0hi[k], c0hi[k], c2a);
        c2b = fmaf(c1lo[k], c1lo[k], c2b); c2b = fmaf(c1hi[k], c1hi[k], c2b);
    }
    const float iv0 = __expf(-2.0f * log_sigmas[o0+0]);
    const float iv1 = __expf(-2.0f * log_sigmas[o0+1]);
    const size_t waveRow0 = ((size_t)blockIdx.x * WAVES + wv) * (size_t)rows_per_wave;
    const float* xb = x + waveRow0 * IN_F;
    float* ob = out + waveRow0 * OUT_F + o0;
    const int rs = lane >> 3, q = lane & 7;
    const int nst = rows_per_wave / RSTAGE;

    float4 vcur = *reinterpret_cast<const float4*>(xb + (size_t)rs*IN_F + q*4);
    float4 vnxt = *reinterpret_cast<const float4*>(xb + (size_t)(RSTAGE+rs)*IN_F + q*4);

    for (int s = 0; s < nst; ++s) {
        const int buf = s & 1;
        float ss = vcur.x*vcur.x; ss = fmaf(vcur.y,vcur.y,ss);
        ss = fmaf(vcur.z,vcur.z,ss); ss = fmaf(vcur.w,vcur.w,ss);
        ss += __shfl_xor(ss,1); ss += __shfl_xor(ss,2); ss += __shfl_xor(ss,4);
        xs[wv][buf][rs][q] = vcur;
        if (q == 0) x2s[wv][buf][rs] = ss;
        vcur = vnxt;
        if (s + 2 < nst)
            vnxt = *reinterpret_cast<const float4*>(
                xb + (size_t)((s+2)*RSTAGE + rs)*IN_F + q*4);
        asm volatile("s_waitcnt lgkmcnt(0)" ::: "memory");
        __builtin_amdgcn_sched_barrier(0);
        #pragma unroll
        for (int rr = 0; rr < RSTAGE; ++rr) {
            f32x2 a0 = {0.f,0.f}, a1 = {0.f,0.f};
            #pragma unroll
            for (int u = 0; u < 4; ++u) {
                const float4 xq = xs[wv][buf][rr][u];
                const f32x2 e0 = {xq.x, xq.y}, e1 = {xq.z, xq.w};
                const f32x2 p00 = {c0lo[4*u+0], c0lo[4*u+1]}, p01 = {c0lo[4*u+2], c0lo[4*u+3]};
                const f32x2 p10 = {c1lo[4*u+0], c1lo[4*u+1]}, p11 = {c1lo[4*u+2], c1lo[4*u+3]};
                a0 = __builtin_elementwise_fma(e0, p00, a0);
                a0 = __builtin_elementwise_fma(e1, p01, a0);
                a1 = __builtin_elementwise_fma(e0, p10, a1);
                a1 = __builtin_elementwise_fma(e1, p11, a1);
            }
            #pragma unroll
            for (int u = 0; u < 4; ++u) {
                const float4 xq = xs[wv][buf][rr][4+u];
                const f32x2 e0 = {xq.x, xq.y}, e1 = {xq.z, xq.w};
                const f32x2 p00 = {c0hi[4*u+0], c0hi[4*u+1]}, p01 = {c0hi[4*u+2], c0hi[4*u+3]};
                const f32x2 p10 = {c1hi[4*u+0], c1hi[4*u+1]}, p11 = {c1hi[4*u+2], c1hi[4*u+3]};
                a0 = __builtin_elementwise_fma(e0, p00, a0);
                a0 = __builtin_elementwise_fma(e1, p01, a0);
                a1 = __builtin_elementwise_fma(e0, p10, a1);
                a1 = __builtin_elementwise_fma(e1, p11, a1);
            }
            const float d0 = a0.x + a0.y, d1 = a1.x + a1.y;
            const float x2 = x2s[wv][buf][rr];
            const float t0 = fmaxf(fmaf(-2.0f,d0,x2+c2a),0.0f);
            const float t1 = fmaxf(fmaf(-2.0f,d1,x2+c2b),0.0f);
            f32x2 o; o.x = __expf(-t0*iv0); o.y = __expf(-t1*iv1);
            __builtin_nontemporal_store(o,
                reinterpret_cast<f32x2*>(ob + (size_t)(s*RSTAGE+rr)*OUT_F));
        }
    }
}

extern "C" void kernel_launch(void* const* d_in, const int* in_sizes, int n_in,
                              void* d_out, int out_size, void* d_ws, size_t ws_size,
                              hipStream_t stream) {
    const float* x          = (const float*)d_in[0];
    const float* centres    = (const float*)d_in[1];
    const float* log_sigmas = (const float*)d_in[2];
    float* out = (float*)d_out;

    const int n = in_sizes[0] / IN_F;      // 1,048,576 rows
    const size_t Q = n / 4;                // 262,144 rows per variant

    // V0: control (R7)
    rbf_v0<<<2048, BLOCK, 0, stream>>>(x, centres, log_sigmas, out, 32);
    // V1: packed pk_fma
    rbf_v1<<<2048, BLOCK, 0, stream>>>(x + Q*IN_F, centres, log_sigmas,
                                       out + Q*OUT_F, 32);
    // V2: packed + barrier-free dbuf
    rbf_v2<<<2048, BLOCK, 0, stream>>>(x + 2*Q*IN_F, centres, log_sigmas,
                                       out + 2*Q*OUT_F, 32);
    // V3: packed at 2x grid (occupancy probe)
    rbf_v1<<<4096, BLOCK, 0, stream>>>(x + 3*Q*IN_F, centres, log_sigmas,
                                       out + 3*Q*OUT_F, 16);
}

// Round 12
// 175.903 us; speedup vs baseline: 1.0336x; 1.0336x over previous
//
#include <hip/hip_runtime.h>

constexpr int IN_F  = 32;
constexpr int OUT_F = 128;
constexpr int BLOCK = 256;
constexpr int WAVES = 4;

using f32x4  = __attribute__((ext_vector_type(4))) float;
using bf16x8 = __attribute__((ext_vector_type(8))) short;

__device__ __forceinline__ short f2bf(float f) {
    unsigned u = __float_as_uint(f);
    u += 0x7fff + ((u >> 16) & 1u);          // RNE to bf16
    return (short)(u >> 16);
}
__device__ __forceinline__ float bf2f(short s) {
    return __uint_as_float(((unsigned)(unsigned short)s) << 16);
}

__global__ __launch_bounds__(BLOCK, 2)
void rbf_mfma(const float* __restrict__ x,
              const float* __restrict__ centres,
              const float* __restrict__ log_sigmas,
              float* __restrict__ out,
              int ntiles)
{
    __shared__ __align__(16) float xtile[WAVES][2][16][32];  // XOR-swizzled rows
    __shared__ float x2s[WAVES][2][16];
    __shared__ __align__(16) float c2s[OUT_F];
    __shared__ __align__(16) float ivs[OUT_F];

    const int tid = threadIdx.x;
    const int wv  = tid >> 6;
    const int l   = tid & 63;

    // ---- per-output ||c||^2 and inv_var tables (fp32 exact) ----
    if (tid < OUT_F) {
        float s = 0.f;
        #pragma unroll
        for (int k = 0; k < IN_F; ++k) {
            const float c = centres[(size_t)tid * IN_F + k];
            s = fmaf(c, c, s);
        }
        c2s[tid] = s;
        ivs[tid] = __expf(-2.0f * log_sigmas[tid]);
    }

    // ---- persistent centre A-fragments, 3-term bf16 split ----
    // A(i,k): i = lane&15 (centre within 16-col tile), k = 8*(lane>>4)+e
    const int rA = l & 15, g = l >> 4;
    bf16x8 chi[8], clo[8];
    #pragma unroll
    for (int t = 0; t < 8; ++t) {
        const float* cp = centres + (size_t)(16 * t + rA) * IN_F + 8 * g;
        #pragma unroll
        for (int e = 0; e < 8; ++e) {
            const float f = cp[e];
            const short h = f2bf(f);
            chi[t][e] = h;
            clo[t][e] = f2bf(f - bf2f(h));
        }
    }
    __syncthreads();

    const size_t row0 = ((size_t)blockIdx.x * WAVES + wv) * (size_t)(ntiles * 16);
    const int r8 = l >> 3;                  // staging: row within 8-row half
    const int bq = l & 7;                   // staging: float4 slot
    const int bs = bq ^ r8;                 // XOR-swizzled slot (bank spread)

    // ---- prologue: stage tile 0 into buf 0 (wave-private, lgkm-only sync) ----
    {
        const float* xg = x + row0 * IN_F;
        const float4 a = *reinterpret_cast<const float4*>(xg + l * 4);        // rows 0-7
        const float4 b = *reinterpret_cast<const float4*>(xg + 256 + l * 4);  // rows 8-15
        float sa = fmaf(a.x,a.x,fmaf(a.y,a.y,fmaf(a.z,a.z,a.w*a.w)));
        float sb = fmaf(b.x,b.x,fmaf(b.y,b.y,fmaf(b.z,b.z,b.w*b.w)));
        sa += __shfl_xor(sa,1); sa += __shfl_xor(sa,2); sa += __shfl_xor(sa,4);
        sb += __shfl_xor(sb,1); sb += __shfl_xor(sb,2); sb += __shfl_xor(sb,4);
        *reinterpret_cast<float4*>(&xtile[wv][0][r8][4*bs]) = a;
        *reinterpret_cast<float4*>(&xtile[wv][0][8+r8][4*bs]) = b;
        if (bq == 0) { x2s[wv][0][r8] = sa; x2s[wv][0][8+r8] = sb; }
        asm volatile("s_waitcnt lgkmcnt(0)" ::: "memory");
        __builtin_amdgcn_sched_barrier(0);
    }

    for (int tt = 0; tt < ntiles; ++tt) {
        const int buf = tt & 1;

        // issue next tile's global loads early (in flight under compute)
        float4 na, nb;
        if (tt + 1 < ntiles) {
            const float* xg = x + (row0 + (size_t)(tt+1)*16) * IN_F;
            na = *reinterpret_cast<const float4*>(xg + l * 4);
            nb = *reinterpret_cast<const float4*>(xg + 256 + l * 4);
        }

        // ---- B fragments (x-tile): lane reads only its 32 B (no broadcast) ----
        // B(k,j): j = lane&15 (x row), k = 8*(lane>>4)+e
        const f32x4 fa = *reinterpret_cast<const f32x4*>(
            &xtile[wv][buf][rA][4 * ((2*g)     ^ (rA & 7))]);
        const f32x4 fb = *reinterpret_cast<const f32x4*>(
            &xtile[wv][buf][rA][4 * ((2*g + 1) ^ (rA & 7))]);
        bf16x8 xhi, xlo;
        #pragma unroll
        for (int e = 0; e < 4; ++e) {
            const short h = f2bf(fa[e]);
            xhi[e] = h; xlo[e] = f2bf(fa[e] - bf2f(h));
        }
        #pragma unroll
        for (int e = 0; e < 4; ++e) {
            const short h = f2bf(fb[e]);
            xhi[4+e] = h; xlo[4+e] = f2bf(fb[e] - bf2f(h));
        }
        const float x2v = x2s[wv][buf][rA];

        float* orow = out + (row0 + (size_t)tt*16 + rA) * OUT_F + 4 * g;
        #pragma unroll
        for (int t = 0; t < 8; ++t) {
            f32x4 acc = {0.f, 0.f, 0.f, 0.f};
            acc = __builtin_amdgcn_mfma_f32_16x16x32_bf16(chi[t], xhi, acc, 0, 0, 0);
            acc = __builtin_amdgcn_mfma_f32_16x16x32_bf16(clo[t], xhi, acc, 0, 0, 0);
            acc = __builtin_amdgcn_mfma_f32_16x16x32_bf16(chi[t], xlo, acc, 0, 0, 0);
            // D(i,j): j = lane&15 = my x-row; i = 16t + 4g + r (4 consecutive cols)
            const f32x4 c24 = *reinterpret_cast<const f32x4*>(&c2s[16*t + 4*g]);
            const f32x4 iv4 = *reinterpret_cast<const f32x4*>(&ivs[16*t + 4*g]);
            f32x4 o;
            #pragma unroll
            for (int r = 0; r < 4; ++r) {
                const float s = fmaxf(fmaf(-2.0f, acc[r], x2v + c24[r]), 0.0f);
                o[r] = __expf(-s * iv4[r]);
            }
            *reinterpret_cast<f32x4*>(orow + 16 * t) = o;   // 64 B/row segments, L2-merged
        }

        // ---- stage next tile into the other buffer ----
        if (tt + 1 < ntiles) {
            const int nbuf = buf ^ 1;
            float sa = fmaf(na.x,na.x,fmaf(na.y,na.y,fmaf(na.z,na.z,na.w*na.w)));
            float sb = fmaf(nb.x,nb.x,fmaf(nb.y,nb.y,fmaf(nb.z,nb.z,nb.w*nb.w)));
            sa += __shfl_xor(sa,1); sa += __shfl_xor(sa,2); sa += __shfl_xor(sa,4);
            sb += __shfl_xor(sb,1); sb += __shfl_xor(sb,2); sb += __shfl_xor(sb,4);
            *reinterpret_cast<float4*>(&xtile[wv][nbuf][r8][4*bs]) = na;
            *reinterpret_cast<float4*>(&xtile[wv][nbuf][8+r8][4*bs]) = nb;
            if (bq == 0) { x2s[wv][nbuf][r8] = sa; x2s[wv][nbuf][8+r8] = sb; }
            asm volatile("s_waitcnt lgkmcnt(0)" ::: "memory");
            __builtin_amdgcn_sched_barrier(0);
        }
    }
}

extern "C" void kernel_launch(void* const* d_in, const int* in_sizes, int n_in,
                              void* d_out, int out_size, void* d_ws, size_t ws_size,
                              hipStream_t stream) {
    const float* x          = (const float*)d_in[0];
    const float* centres    = (const float*)d_in[1];
    const float* log_sigmas = (const float*)d_in[2];
    float* out = (float*)d_out;

    const int n = in_sizes[0] / IN_F;           // 1,048,576 rows
    const int blocks = 2048;
    const int ntiles = n / (blocks * WAVES * 16);   // 8 tiles of 16 rows per wave
    rbf_mfma<<<blocks, BLOCK, 0, stream>>>(x, centres, log_sigmas, out, ntiles);
}

// Round 14
// 154.743 us; speedup vs baseline: 1.1749x; 1.1367x over previous
//
#include <hip/hip_runtime.h>

constexpr int IN_F   = 32;
constexpr int OUT_F  = 128;
constexpr int BLOCK  = 256;
constexpr int WAVES  = BLOCK / 64;
constexpr int RSTAGE = 8;

using f32x2  = __attribute__((ext_vector_type(2)))  float;
using f32x4  = __attribute__((ext_vector_type(4)))  float;
using f32x16 = __attribute__((ext_vector_type(16))) float;

// ---------------- R7 kernel (best known: 152.7 us) ----------------
__global__ __launch_bounds__(BLOCK, 4)
void rbf_kernel(const float* __restrict__ x,
                const float* __restrict__ centres,
                const float* __restrict__ log_sigmas,
                float* __restrict__ out,
                int rows_per_wave)
{
    __shared__ float4 xs[WAVES][RSTAGE][IN_F / 4];
    __shared__ float  x2s[WAVES][RSTAGE];

    const int tid = threadIdx.x, wv = tid >> 6, lane = tid & 63;
    const int o0 = lane * 2;
    const f32x16 c0lo = *reinterpret_cast<const f32x16*>(centres + (size_t)(o0+0)*IN_F);
    const f32x16 c0hi = *reinterpret_cast<const f32x16*>(centres + (size_t)(o0+0)*IN_F + 16);
    const f32x16 c1lo = *reinterpret_cast<const f32x16*>(centres + (size_t)(o0+1)*IN_F);
    const f32x16 c1hi = *reinterpret_cast<const f32x16*>(centres + (size_t)(o0+1)*IN_F + 16);

    float c2a = 0.f, c2b = 0.f;
    #pragma unroll
    for (int k = 0; k < 16; ++k) {
        c2a = fmaf(c0lo[k], c0lo[k], c2a); c2a = fmaf(c0hi[k], c0hi[k], c2a);
        c2b = fmaf(c1lo[k], c1lo[k], c2b); c2b = fmaf(c1hi[k], c1hi[k], c2b);
    }
    const float iv0 = __expf(-2.0f * log_sigmas[o0+0]);
    const float iv1 = __expf(-2.0f * log_sigmas[o0+1]);
    const size_t waveRow0 = ((size_t)blockIdx.x * WAVES + wv) * (size_t)rows_per_wave;
    const int rs = lane >> 3, q = lane & 7;

    for (int it = 0; it < rows_per_wave; it += RSTAGE) {
        const float4 v = *reinterpret_cast<const float4*>(x + (waveRow0+it)*IN_F + lane*4);
        float ss = v.x*v.x; ss = fmaf(v.y,v.y,ss); ss = fmaf(v.z,v.z,ss); ss = fmaf(v.w,v.w,ss);
        ss += __shfl_xor(ss,1); ss += __shfl_xor(ss,2); ss += __shfl_xor(ss,4);
        xs[wv][rs][q] = v;
        if (q == 0) x2s[wv][rs] = ss;
        __syncthreads();
        #pragma unroll
        for (int rr = 0; rr < RSTAGE; ++rr) {
            float acc0 = 0.f, acc1 = 0.f;
            #pragma unroll
            for (int u = 0; u < 4; ++u) {
                const float4 xq = xs[wv][rr][u];
                acc0 = fmaf(xq.x,c0lo[4*u+0],acc0); acc0 = fmaf(xq.y,c0lo[4*u+1],acc0);
                acc0 = fmaf(xq.z,c0lo[4*u+2],acc0); acc0 = fmaf(xq.w,c0lo[4*u+3],acc0);
                acc1 = fmaf(xq.x,c1lo[4*u+0],acc1); acc1 = fmaf(xq.y,c1lo[4*u+1],acc1);
                acc1 = fmaf(xq.z,c1lo[4*u+2],acc1); acc1 = fmaf(xq.w,c1lo[4*u+3],acc1);
            }
            #pragma unroll
            for (int u = 0; u < 4; ++u) {
                const float4 xq = xs[wv][rr][4+u];
                acc0 = fmaf(xq.x,c0hi[4*u+0],acc0); acc0 = fmaf(xq.y,c0hi[4*u+1],acc0);
                acc0 = fmaf(xq.z,c0hi[4*u+2],acc0); acc0 = fmaf(xq.w,c0hi[4*u+3],acc0);
                acc1 = fmaf(xq.x,c1hi[4*u+0],acc1); acc1 = fmaf(xq.y,c1hi[4*u+1],acc1);
                acc1 = fmaf(xq.z,c1hi[4*u+2],acc1); acc1 = fmaf(xq.w,c1hi[4*u+3],acc1);
            }
            const float x2 = x2s[wv][rr];
            const float t0 = fmaxf(fmaf(-2.0f,acc0,x2+c2a),0.0f);
            const float t1 = fmaxf(fmaf(-2.0f,acc1,x2+c2b),0.0f);
            f32x2 o; o.x = __expf(-t0*iv0); o.y = __expf(-t1*iv1);
            __builtin_nontemporal_store(o,
                reinterpret_cast<f32x2*>(out + (waveRow0+it+rr)*OUT_F + o0));
        }
        __syncthreads();
    }
}

// -------- mixed-stream probe: idempotent full-buffer self-copy --------
// Reads d_out and writes the identical values back (output unchanged).
// 512 MB read + 512 MB write per pass, NT both ways to defeat L3 absorption.
__global__ __launch_bounds__(BLOCK)
void out_selfcopy(f32x4* __restrict__ p, size_t n4)
{
    const size_t stride = (size_t)gridDim.x * blockDim.x;
    for (size_t i = (size_t)blockIdx.x * blockDim.x + threadIdx.x; i < n4; i += stride) {
        const f32x4 v = __builtin_nontemporal_load(&p[i]);
        __builtin_nontemporal_store(v, &p[i]);
    }
}

extern "C" void kernel_launch(void* const* d_in, const int* in_sizes, int n_in,
                              void* d_out, int out_size, void* d_ws, size_t ws_size,
                              hipStream_t stream) {
    const float* x          = (const float*)d_in[0];
    const float* centres    = (const float*)d_in[1];
    const float* log_sigmas = (const float*)d_in[2];
    float* out = (float*)d_out;

    const int n = in_sizes[0] / IN_F;                   // 1,048,576 rows
    const int blocks = 2048;
    const int rows_per_wave = (n / blocks) / WAVES;     // 128

    // dispatch 1: the real kernel (correct output, ~152.7 us)
    rbf_kernel<<<blocks, BLOCK, 0, stream>>>(x, centres, log_sigmas, out, rows_per_wave);

    // dispatches 2+3: pure mixed-stream bandwidth probe (idempotent)
    const size_t n4 = (size_t)out_size / 4;             // 32M f32x4 = 512 MB
    out_selfcopy<<<blocks, BLOCK, 0, stream>>>((f32x4*)d_out, n4);
    out_selfcopy<<<blocks, BLOCK, 0, stream>>>((f32x4*)d_out, n4);
}